// Round 18
// baseline (33032.578 us; speedup 1.0000x reference)
//
#include <hip/hip_runtime.h>
#include <hip/hip_bf16.h>

// Dual-chain phase-shifted decoder v8. 256 blocks x 256 thr (4 waves).
// Batch split into chain A (rows 0:1024) and chain B (1024:2048) - fully
// independent recurrences. Each block owns, PER CHAIN: 16 rows (mtile=bk>>2)
// x 128 j-cols (ntile=bk&3); group = 4 consecutive blocks. Per iteration:
//   GEMM(A,t) -> GEMM(B,t) -> ATTN(A,t+1) -> ATTN(B,t+1)
// Every wait(n) has one full other-chain phase between the producer's post()
// and the wait -> barrier/exchange latency hidden by construction (R16 showed
// co-resident blocks stall in lockstep; phase shift must be intra-block).
// post(): waitv0 + syncthreads + tid0 sc-flag store. wait(n): 4-flag sc poll.
// All exchange via sc0/sc1 L3-coherent ops (R9-proven). Wbig bf16 from L2.

typedef __attribute__((ext_vector_type(8))) short short8;
typedef __attribute__((ext_vector_type(4))) float floatx4;
typedef __attribute__((ext_vector_type(2))) unsigned int uint2v;

#define DEV static __device__ __forceinline__
#define C2LE 2.885390082f    // 2*log2(e)
#define LOG2E 1.4426950409f
#define LN2 0.6931471806f

DEV unsigned short f2bf(float f) {
    unsigned int u = __float_as_uint(f);
    unsigned int r = (u + 0x7FFFu + ((u >> 16) & 1u)) >> 16;
    return (unsigned short)r;
}
DEV float bf2f(unsigned short u) { return __uint_as_float(((unsigned int)u) << 16); }
DEV float rcp_f(float x) { float r; asm("v_rcp_f32 %0, %1" : "=v"(r) : "v"(x)); return r; }
DEV float tanh_f(float x) { return 1.f - 2.f * rcp_f(1.f + exp2f(x * C2LE)); }
DEV float sigm(float x) { return rcp_f(1.f + exp2f(-x * LOG2E)); }

// ---- L3-coherent (L1+L2 bypass) helpers [R9-R16 proven] ----
DEV void ldg16_sc(short8* d, const unsigned short* p) {
    asm volatile("global_load_dwordx4 %0, %1, off sc0 sc1" : "=v"(*d) : "v"(p));
}
DEV void stg16_sc(unsigned short* p, short8 v) {
    asm volatile("global_store_dwordx4 %0, %1, off sc0 sc1" :: "v"(p), "v"(v) : "memory");
}
DEV void stg8_sc(unsigned short* p, uint2v v) {
    asm volatile("global_store_dwordx2 %0, %1, off sc0 sc1" :: "v"(p), "v"(v) : "memory");
}
DEV void st_flag(int* p, int v) {
    asm volatile("global_store_dword %0, %1, off sc0 sc1" :: "v"(p), "v"(v) : "memory");
}
DEV int ld_flag(const int* p) {
    int v;
    asm volatile("global_load_dword %0, %1, off sc0 sc1\n\ts_waitcnt vmcnt(0)"
                 : "=v"(v) : "v"(p) : "memory");
    return v;
}
DEV void waitv0() { asm volatile("s_waitcnt vmcnt(0)" ::: "memory"); }

// ---------------- workspace layout (bytes) ----------------
#define OFF_XH     ((size_t)0)          // bf16 [2048][576]: h|x|ctx|pad0(20)
#define OFF_C0     ((size_t)2359296)    // f32 [2048][512]
#define OFF_PARTS  ((size_t)6553600)    // bf16 [2048][64][32]
#define OFF_WBIG   ((size_t)14942208)   // bf16 [2048][576], perm p=4j+g <- orig g*512+j
#define OFF_WSMALL ((size_t)17301504)   // bf16 [160][512]
#define OFF_WW2    ((size_t)17465344)   // bf16 [128][32] = C2LE*Ww
#define OFF_BIAS   ((size_t)17473536)   // f32 [2048]
#define OFF_AVG    ((size_t)17481728)   // f32 [2048][64]
#define OFF_FLAGS  ((size_t)18006016)   // int [256*32]

__global__ void k_init(int* flags) {
    int i = blockIdx.x * 256 + threadIdx.x;
    if (i < 256 * 32) flags[i] = 0;
}

__global__ void k_avg(const float* __restrict__ img, float* __restrict__ avg) {
    int idx = blockIdx.x * 256 + threadIdx.x;
    int b = idx >> 6, p = idx & 63;
    const float* base = img + (size_t)b * 2048 + p;
    float s = 0.f;
#pragma unroll
    for (int k = 0; k < 32; ++k) s += base[k * 64];
    avg[idx] = s * (1.f / 32.f);
}

__global__ void k_prep(const float* __restrict__ Whh, const float* __restrict__ Wih,
                       const float* __restrict__ Uw, const float* __restrict__ betaw,
                       const float* __restrict__ Ww, const float* __restrict__ bih,
                       const float* __restrict__ bhh,
                       unsigned short* __restrict__ Wbig, unsigned short* __restrict__ Wsmall,
                       unsigned short* __restrict__ Ww2, float* __restrict__ bias_cat) {
    int p = blockIdx.x, tid = threadIdx.x;
    int g = p & 3, j = p >> 2, orig = g * 512 + j;
    for (int k = tid; k < 576; k += 256) {
        float v = 0.f;
        if (k < 512) v = Whh[(size_t)orig * 512 + k];
        else if (k < 556) v = Wih[(size_t)orig * 44 + (k - 512)];
        Wbig[(size_t)p * 576 + k] = f2bf(v);
    }
    if (p < 160) {
        for (int k = tid; k < 512; k += 256) {
            float v = (p < 128) ? Uw[(size_t)p * 512 + k] : betaw[(size_t)(p - 128) * 512 + k];
            Wsmall[(size_t)p * 512 + k] = f2bf(v);
        }
    }
    if (p < 128 && tid < 32) Ww2[p * 32 + tid] = f2bf(C2LE * Ww[p * 32 + tid]);
    if (tid == 0) bias_cat[orig] = bih[orig] + bhh[orig];
}

__global__ __launch_bounds__(512) void k_h0c0(const float* __restrict__ avg,
                                              const float* __restrict__ ihw, const float* __restrict__ ihb,
                                              const float* __restrict__ icw, const float* __restrict__ icb,
                                              unsigned short* __restrict__ xh, float* __restrict__ c0) {
    __shared__ float avg_s[8][64];
    int b0 = blockIdx.x * 8, tid = threadIdx.x;
    for (int i = tid; i < 8 * 64; i += 512) avg_s[i >> 6][i & 63] = avg[b0 * 64 + i];
    __syncthreads();
    int j = tid;
    float w0[64];
#pragma unroll
    for (int p4 = 0; p4 < 16; ++p4) {
        float4 v = ((const float4*)(ihw + j * 64))[p4];
        w0[p4 * 4 + 0] = v.x; w0[p4 * 4 + 1] = v.y; w0[p4 * 4 + 2] = v.z; w0[p4 * 4 + 3] = v.w;
    }
    float bh = ihb[j];
#pragma unroll
    for (int bb = 0; bb < 8; ++bb) {
        float s = bh;
#pragma unroll
        for (int p = 0; p < 64; ++p) s += w0[p] * avg_s[bb][p];
        xh[(size_t)(b0 + bb) * 576 + j] = f2bf(tanh_f(s));
        if (j < 20) xh[(size_t)(b0 + bb) * 576 + 556 + j] = 0;
    }
#pragma unroll
    for (int p4 = 0; p4 < 16; ++p4) {
        float4 v = ((const float4*)(icw + j * 64))[p4];
        w0[p4 * 4 + 0] = v.x; w0[p4 * 4 + 1] = v.y; w0[p4 * 4 + 2] = v.z; w0[p4 * 4 + 3] = v.w;
    }
    float bc = icb[j];
#pragma unroll
    for (int bb = 0; bb < 8; ++bb) {
        float s = bc;
#pragma unroll
        for (int p = 0; p < 64; ++p) s += w0[p] * avg_s[bb][p];
        c0[(size_t)(b0 + bb) * 512 + j] = tanh_f(s);
    }
}

// parts_bf[b][p][k] = bf16(img[b][k][p])
__global__ __launch_bounds__(256) void k_parts(const float* __restrict__ img,
                                               unsigned short* __restrict__ parts_bf) {
    __shared__ float pl[64][33];
    int b = blockIdx.x, tid = threadIdx.x;
    const float* ib = img + (size_t)b * 2048;
    for (int i = tid; i < 2048; i += 256) pl[i & 63][i >> 6] = ib[i];
    __syncthreads();
    for (int i = tid; i < 2048; i += 256)
        parts_bf[(size_t)b * 2048 + i] = f2bf(pl[i >> 5][i & 31]);
}

__global__ __launch_bounds__(256, 2) void k_scan(
    unsigned short* __restrict__ xh,
    const float* __restrict__ c0,
    const unsigned short* __restrict__ parts_bf,
    const unsigned short* __restrict__ Wsmall, const unsigned short* __restrict__ Wbig,
    const unsigned short* __restrict__ Ww2, const float* __restrict__ bias_cat,
    const float* __restrict__ Ub, const float* __restrict__ betab, const float* __restrict__ Wb,
    const float* __restrict__ vw,
    const float* __restrict__ label, const float* __restrict__ ow, const float* __restrict__ ob,
    float* __restrict__ out_alpha, float* __restrict__ out_logits,
    int* __restrict__ flags)
{
    __shared__ unsigned short Ald[2][16 * 584];   // 37.4 KB per-chain A-tiles
    __shared__ unsigned short ow_l[12][512];      // 12.3 KB
    __shared__ unsigned short h2scr[16][128];     // 4 KB   (phase-local, shared)
    __shared__ float uh_l[16][160];               // 10.2 KB (phase-local, shared)
    __shared__ float al_l[4][64];                 // 1 KB
    __shared__ float bias_l[512];                 // 2 KB
    __shared__ unsigned short xscr[4][48];
    __shared__ float vw2_l[128];
    __shared__ float obl[12];

    const int tid = threadIdx.x, w = tid >> 6, lane = tid & 63;  // 4 waves
    const int bk = blockIdx.x;
    const int mtile = bk >> 2, ntile = bk & 3;
    const int g4 = bk & ~3;

    // ---- one-time LDS staging ----
    if (tid < 128) vw2_l[tid] = -2.f * vw[tid];
    if (tid < 12) obl[tid] = ob[tid];
    for (int i = tid; i < 512; i += 256) {
        int g = i >> 7, jl = i & 127;
        bias_l[i] = bias_cat[g * 512 + ntile * 128 + jl];
    }
    for (int i = tid; i < 12 * 512; i += 256) ow_l[i >> 9][i & 511] = f2bf(ow[i]);
#pragma unroll
    for (int c = 0; c < 2; ++c)
        for (int i = tid; i < 16 * 20; i += 256) {
            int row = i / 20, cc = 556 + (i % 20);
            Ald[c][row * 584 + cc] = 0;
        }
    // c registers per chain: (b, j) = (c*1024 + mtile*16 + (lane>>4)*4 + r,
    //                                  ntile*128 + w*32 + nf*4 + (lane&3))
    float cregA[32], cregB[32];
#pragma unroll
    for (int nf = 0; nf < 8; ++nf)
#pragma unroll
        for (int r = 0; r < 4; ++r) {
            int br = mtile * 16 + (lane >> 4) * 4 + r;
            int j = ntile * 128 + w * 32 + nf * 4 + (lane & 3);
            cregA[nf * 4 + r] = c0[(size_t)br * 512 + j];
            cregB[nf * 4 + r] = c0[(size_t)(1024 + br) * 512 + j];
        }

    float vwsum = 0.f;
    int bc = 0;                 // monotonic post counter (uniform across block)
    int xpostA = 0, xpostB = 0, hpostA = 0, hpostB = 0;

    // ---- primitives ----
    auto post = [&]() {
        waitv0();
        __syncthreads();
        if (tid == 0) st_flag(flags + bk * 32, bc + 1);
        ++bc;
    };
    auto wait_n = [&](int n) {
        if (tid < 64) {
            for (;;) {
                int v = n;
                if (lane < 4) v = ld_flag(flags + (g4 + lane) * 32);
                if (__all(v >= n)) break;
                __builtin_amdgcn_s_sleep(1);
            }
        }
        __syncthreads();
    };

    // ---- per-chain helpers (chain base row = cb = c*1024 + mtile*16) ----
    auto stage16 = [&](unsigned short* A, int cb) {
        short8 tv[4];
#pragma unroll
        for (int q = 0; q < 4; ++q) {
            int cid = tid + q * 256;
            int row = cid >> 6, c16 = cid & 63;
            ldg16_sc(&tv[q], xh + (size_t)(cb + row) * 576 + c16 * 8);
        }
        waitv0();
        __builtin_amdgcn_sched_barrier(0);
#pragma unroll
        for (int q = 0; q < 4; ++q) {
            int cid = tid + q * 256;
            int row = cid >> 6, c16 = cid & 63;
            *(short8*)&A[row * 584 + c16 * 8] = tv[q];
        }
    };
    auto stage_tail = [&](unsigned short* A, int cb) {
        if (tid < 128) {
            short8 tv;
            int row = tid >> 3, c16 = tid & 7;
            ldg16_sc(&tv, xh + (size_t)(cb + row) * 576 + 512 + c16 * 8);
            waitv0();
            __builtin_amdgcn_sched_barrier(0);
            *(short8*)&A[row * 584 + 512 + c16 * 8] = tv;
        }
    };
    auto do_uh = [&](const unsigned short* A) {
        for (int nt = w; nt < 10; nt += 4) {
            const unsigned short* Bp = Wsmall + (size_t)(nt * 16 + (lane & 15)) * 512 + (lane >> 4) * 8;
            const unsigned short* Ab = &A[(lane & 15) * 584 + (lane >> 4) * 8];
            floatx4 u = {};
#pragma unroll 4
            for (int k0 = 0; k0 < 512; k0 += 32) {
                short8 a = *(const short8*)(Ab + k0);
                u = __builtin_amdgcn_mfma_f32_16x16x32_bf16(a, *(const short8*)(Bp + k0), u, 0, 0, 0);
            }
            int n = nt * 16 + (lane & 15), r0 = (lane >> 4) * 4;
            float addv = (n < 128) ? (Ub[n] + Wb[n]) : betab[n - 128];
            float scl = (n < 128) ? C2LE : 1.f;
#pragma unroll
            for (int r = 0; r < 4; ++r) uh_l[r0 + r][n] = (u[r] + addv) * scl;
        }
    };
    auto do_head = [&](const unsigned short* A, int cb, int tt) {
        int lr = ntile * 4 + w;
        int b = cb + lr;
        short8 hv = *(const short8*)&A[lr * 584 + lane * 8];
        float hf[8];
#pragma unroll
        for (int j = 0; j < 8; ++j) hf[j] = bf2f((unsigned short)hv[j]);
        float ov[12];
#pragma unroll
        for (int v = 0; v < 12; ++v) {
            short8 wv = *(const short8*)&ow_l[v][lane * 8];
            float p = 0.f;
#pragma unroll
            for (int j = 0; j < 8; ++j) p += hf[j] * bf2f((unsigned short)wv[j]);
#pragma unroll
            for (int o = 32; o; o >>= 1) p += __shfl_xor(p, o);
            ov[v] = p + obl[v];
        }
        float mx = ov[0];
#pragma unroll
        for (int v = 1; v < 12; ++v) mx = fmaxf(mx, ov[v]);
        float ss = 0.f;
#pragma unroll
        for (int v = 0; v < 12; ++v) ss += exp2f((ov[v] - mx) * LOG2E);
        float lse = mx + log2f(ss) * LN2;
#pragma unroll
        for (int v = 0; v < 12; ++v)
            if (lane == v) out_logits[((size_t)b * 256 + tt) * 12 + v] = ov[v] - lse;
    };
    auto do_attn = [&](int cb, int tt) {      // owner rows, 1 per wave
        int lr = ntile * 4 + w;
        int b = cb + lr;
        const unsigned short* pb = parts_bf + (size_t)b * 2048;
        short8 pa[4];
#pragma unroll
        for (int mt = 0; mt < 4; ++mt)
            pa[mt] = *(const short8*)(pb + ((lane & 15) + 16 * mt) * 32 + (lane >> 4) * 8);
        float sc[4][4] = {};
#pragma unroll
        for (int nt = 0; nt < 8; ++nt) {
            short8 wwf = *(const short8*)(Ww2 + (size_t)((lane & 15) + 16 * nt) * 32 + (lane >> 4) * 8);
            int d = nt * 16 + (lane & 15);
            float ud = uh_l[lr][d];
            float v2 = vw2_l[d];
            floatx4 ini = {ud, ud, ud, ud};
#pragma unroll
            for (int mt = 0; mt < 4; ++mt) {
                floatx4 wsa = __builtin_amdgcn_mfma_f32_16x16x32_bf16(pa[mt], wwf, ini, 0, 0, 0);
#pragma unroll
                for (int r = 0; r < 4; ++r)
                    sc[mt][r] += v2 * rcp_f(1.f + exp2f(wsa[r]));
            }
        }
        float mx = -1e30f;
#pragma unroll
        for (int mt = 0; mt < 4; ++mt)
#pragma unroll
            for (int r = 0; r < 4; ++r) {
                float s = sc[mt][r];
                s += __shfl_xor(s, 1); s += __shfl_xor(s, 2);
                s += __shfl_xor(s, 4); s += __shfl_xor(s, 8);
                s += vwsum;
                sc[mt][r] = s;
                mx = fmaxf(mx, s);
            }
        mx = fmaxf(mx, __shfl_xor(mx, 16));
        mx = fmaxf(mx, __shfl_xor(mx, 32));
        float ssum = 0.f;
        float av[4][4];
#pragma unroll
        for (int mt = 0; mt < 4; ++mt)
#pragma unroll
            for (int r = 0; r < 4; ++r) {
                av[mt][r] = exp2f((sc[mt][r] - mx) * LOG2E);
                ssum += av[mt][r];
            }
        ssum += __shfl_xor(ssum, 16);
        ssum += __shfl_xor(ssum, 32);
        float rs = rcp_f(ssum);
#pragma unroll
        for (int mt = 0; mt < 4; ++mt) {
            if ((lane & 15) == mt) {
                float4 fv = make_float4(av[mt][0] * rs, av[mt][1] * rs, av[mt][2] * rs, av[mt][3] * rs);
                int p0 = mt * 16 + (lane >> 4) * 4;
                *(float4*)&out_alpha[((size_t)tt * 2048 + b) * 64 + p0] = fv;
                *(float4*)&al_l[w][p0] = fv;
            }
        }
        int k = lane & 31, half = lane >> 5;
        float cp = 0.f;
#pragma unroll
        for (int p = 0; p < 32; ++p) {
            int pp = half * 32 + p;
            cp += al_l[w][pp] * bf2f(pb[pp * 32 + k]);
        }
        cp += __shfl_xor(cp, 32);
        if (half == 0) xscr[w][12 + k] = f2bf(cp * sigm(uh_l[lr][128 + k]));
        if (lane < 12) xscr[w][lane] = f2bf(label[((size_t)b * 256 + tt) * 12 + lane]);
        if (lane < 11) {
            uint2v v = *(const uint2v*)&xscr[w][lane * 4];
            stg8_sc(xh + (size_t)b * 576 + 512 + lane * 4, v);
        }
    };
    auto gemm_cell = [&](const unsigned short* A, int cb, float* creg) {
        const unsigned short* Bp = Wbig + (size_t)(ntile * 512 + w * 128 + (lane & 15)) * 576 + (lane >> 4) * 8;
        const unsigned short* Ab = &A[(lane & 15) * 584 + (lane >> 4) * 8];
        floatx4 acc[8];
#pragma unroll
        for (int nf = 0; nf < 8; ++nf) acc[nf] = (floatx4){0.f, 0.f, 0.f, 0.f};
#pragma unroll 2
        for (int kk = 0; kk < 18; ++kk) {
            int k0 = kk * 32;
            short8 a = *(const short8*)(Ab + k0);
#pragma unroll
            for (int nf = 0; nf < 8; ++nf) {
                short8 bv = *(const short8*)(Bp + (size_t)nf * 9216 + k0);
                acc[nf] = __builtin_amdgcn_mfma_f32_16x16x32_bf16(a, bv, acc[nf], 0, 0, 0);
            }
        }
        int base = (lane & 48) | ((lane & 3) * 4);
#pragma unroll
        for (int nf = 0; nf < 8; ++nf) {
            int jl = w * 32 + nf * 4 + (lane & 3);
            float bi = bias_l[jl], bfv = bias_l[128 + jl], bg = bias_l[256 + jl], bo = bias_l[384 + jl];
#pragma unroll
            for (int r = 0; r < 4; ++r) {
                float x = acc[nf][r];
                float g0 = __shfl(x, base + 0);
                float g1 = __shfl(x, base + 1);
                float g2 = __shfl(x, base + 2);
                float g3 = __shfl(x, base + 3);
                int ci = nf * 4 + r;
                float c2 = sigm(g1 + bfv) * creg[ci] + sigm(g0 + bi) * tanh_f(g2 + bg);
                creg[ci] = c2;
                float h2 = sigm(g3 + bo) * tanh_f(c2);
                if (((lane >> 2) & 3) == 0) {
                    int row = (lane >> 4) * 4 + r;
                    h2scr[row][jl] = f2bf(h2);
                }
            }
        }
        __syncthreads();   // h2scr complete
        {   // coalesced publish: 256 thr x 16B = 16 rows x 128 cols
            int row = tid >> 4, seg = tid & 15;
            short8 v = *(const short8*)&h2scr[row][seg * 8];
            stg16_sc(xh + (size_t)(cb + row) * 576 + ntile * 128 + seg * 8, v);
        }
    };

    const int cbA = mtile * 16, cbB = 1024 + mtile * 16;

    // ---- prologue ----
    stage16(Ald[0], cbA);
    stage16(Ald[1], cbB);
    __syncthreads();
    {
        float s = 0.f;
#pragma unroll
        for (int d = 0; d < 128; ++d) s += vw2_l[d];
        vwsum = -0.5f * s;
    }
    do_uh(Ald[0]);
    __syncthreads();
    do_attn(cbA, 0);           // publishes x_A(0)
    post(); xpostA = bc;
    do_uh(Ald[1]);
    __syncthreads();
    do_attn(cbB, 0);           // publishes x_B(0)
    post(); xpostB = bc;

    for (int t = 0; t < 256; ++t) {
        // ---- GEMM(A, t) ----
        wait_n(xpostA);
        stage_tail(Ald[0], cbA);
        __syncthreads();
        gemm_cell(Ald[0], cbA, cregA);    // publishes h_A(t+1)
        post(); hpostA = bc;
        // ---- GEMM(B, t) ----
        wait_n(xpostB);
        stage_tail(Ald[1], cbB);
        __syncthreads();
        gemm_cell(Ald[1], cbB, cregB);    // publishes h_B(t+1)
        post(); hpostB = bc;
        // ---- ATTN(A, t+1) ----
        wait_n(hpostA);
        stage16(Ald[0], cbA);
        __syncthreads();
        do_head(Ald[0], cbA, t);          // logits(t) from h(t+1)
        if (t < 255) {
            do_uh(Ald[0]);
            __syncthreads();
            do_attn(cbA, t + 1);          // publishes x_A(t+1)
            post(); xpostA = bc;
        }
        // ---- ATTN(B, t+1) ----
        wait_n(hpostB);
        stage16(Ald[1], cbB);
        __syncthreads();
        do_head(Ald[1], cbB, t);
        if (t < 255) {
            do_uh(Ald[1]);
            __syncthreads();
            do_attn(cbB, t + 1);          // publishes x_B(t+1)
            post(); xpostB = bc;
        }
    }
}

extern "C" void kernel_launch(void* const* d_in, const int* in_sizes, int n_in,
                              void* d_out, int out_size, void* d_ws, size_t ws_size,
                              hipStream_t stream) {
    const float* img   = (const float*)d_in[0];
    const float* label = (const float*)d_in[1];
    const float* Ww    = (const float*)d_in[2];
    const float* Wb    = (const float*)d_in[3];
    const float* Uw    = (const float*)d_in[4];
    const float* Ub    = (const float*)d_in[5];
    const float* vw    = (const float*)d_in[6];
    // d_in[7] = vb (cancels in softmax)
    const float* betaw = (const float*)d_in[8];
    const float* betab = (const float*)d_in[9];
    const float* ihw   = (const float*)d_in[10];
    const float* ihb   = (const float*)d_in[11];
    const float* icw   = (const float*)d_in[12];
    const float* icb   = (const float*)d_in[13];
    const float* Wih   = (const float*)d_in[14];
    const float* Whh   = (const float*)d_in[15];
    const float* bih   = (const float*)d_in[16];
    const float* bhh   = (const float*)d_in[17];
    const float* ow    = (const float*)d_in[18];
    const float* ob    = (const float*)d_in[19];

    char* ws = (char*)d_ws;
    unsigned short* xh       = (unsigned short*)(ws + OFF_XH);
    float*          c0       = (float*)(ws + OFF_C0);
    unsigned short* parts_bf = (unsigned short*)(ws + OFF_PARTS);
    unsigned short* Wbig     = (unsigned short*)(ws + OFF_WBIG);
    unsigned short* Wsmall   = (unsigned short*)(ws + OFF_WSMALL);
    unsigned short* Ww2      = (unsigned short*)(ws + OFF_WW2);
    float*          bias     = (float*)(ws + OFF_BIAS);
    float*          avg      = (float*)(ws + OFF_AVG);
    int*            flags    = (int*)(ws + OFF_FLAGS);

    float* out_logits = (float*)d_out;
    float* out_alpha  = out_logits + (size_t)2048 * 256 * 12;

    k_init<<<32, 256, 0, stream>>>(flags);
    k_avg<<<512, 256, 0, stream>>>(img, avg);
    k_prep<<<2048, 256, 0, stream>>>(Whh, Wih, Uw, betaw, Ww, bih, bhh, Wbig, Wsmall, Ww2, bias);
    k_h0c0<<<256, 512, 0, stream>>>(avg, ihw, ihb, icw, icb, xh, c0);
    k_parts<<<2048, 256, 0, stream>>>(img, parts_bf);

    k_scan<<<256, 256, 0, stream>>>(xh, c0, parts_bf, Wsmall, Wbig, Ww2, bias,
                                    Ub, betab, Wb, vw, label, ow, ob,
                                    out_alpha, out_logits, flags);
}